// Round 1
// 224.392 us; speedup vs baseline: 1.0655x; 1.0655x over previous
//
#include <hip/hip_runtime.h>
#include <hip/hip_bf16.h>

// MultiAttentionHead: B=2, T=2048, E=1024, H=16, D=64
// Inputs (fp32): x[B,T,E], Wq[H,E,D], Wk[H,E,D], Wv[H,E,D], Wo[E,E]
// Output (fp32): combined @ Wo + x   [B,T,E]
//
// ws layout (ushort=fp16 elements):
//   xh/comb : 0        .. 4M    (x fp16, later overwritten by attn output)
//   wt      : 4M       .. 7.34M ([p][h][d][e] transposed QKV weights)
//   wot     : 7.34M    .. 8.39M ([j][e] transposed Wo)
//   q : 8.39M  k : 12.58M  vt : 16.78M .. 21.24M  (total ~42.5 MB)
//
// r10 lesson: GEMM fragment gathers stage through LDS with lane-contiguous
// loads (address-pipe saturation otherwise).
// r11 (this round): attn softmax entirely in-register. Swapped QK^T
// (mfma(K,Q) -> S^T) puts each q-row's keys lane-local; the exp'd values are
// directly the A-fragment of mfma_f32_16x16x16f16 for PV. P never touches
// LDS (removes the ds_write_b16 bank conflicts + lgkm chain). K/V staging is
// double-buffered with loads issued a full tile early.

#define B_ 2
#define T_ 2048
#define E_ 1024
#define H_ 16
#define D_ 64
#define VTS_ 2176   // padded vt leading dim (elements)
#define LD_ 72      // LDS tile row stride (elements; 64 + 8, keeps 16B align)

typedef _Float16 h8 __attribute__((ext_vector_type(8)));
typedef _Float16 h4 __attribute__((ext_vector_type(4)));
typedef float f32x4 __attribute__((ext_vector_type(4)));

union U4 { uint4 u; h8 h; };

__device__ __forceinline__ float h2f(unsigned short s) {
  _Float16 h;
  __builtin_memcpy(&h, &s, 2);
  return (float)h;
}

__device__ __forceinline__ unsigned short f2h(float f) {
  _Float16 h = (_Float16)f;
  unsigned short s;
  __builtin_memcpy(&s, &h, 2);
  return s;
}

// ---------------------------------------------------------------------------
// Prep 0: x fp32 -> fp16.  grid = B*T*E/1024, block=256.
// ---------------------------------------------------------------------------
__global__ __launch_bounds__(256) void cvt_x(const float* __restrict__ x,
                                             unsigned short* __restrict__ xh) {
  const size_t i = ((size_t)blockIdx.x * 256 + threadIdx.x) * 4;
  const float4 f = *(const float4*)(x + i);
  ushort4 pk;
  pk.x = f2h(f.x); pk.y = f2h(f.y); pk.z = f2h(f.z); pk.w = f2h(f.w);
  *(ushort4*)(xh + i) = pk;
}

// ---------------------------------------------------------------------------
// Prep 1: Wq/Wk/Wv [h][e][d] fp32 -> wt [p][h][d][e] fp16. grid=(16,16,3).
// ---------------------------------------------------------------------------
__global__ __launch_bounds__(256) void tconv_w(
    const float* __restrict__ Wq, const float* __restrict__ Wk,
    const float* __restrict__ Wv, unsigned short* __restrict__ wt) {
  __shared__ float ts[64][65];
  const int p = blockIdx.z, h = blockIdx.y;
  const float* src = ((p == 0) ? Wq : (p == 1) ? Wk : Wv) + (size_t)h * E_ * D_;
  unsigned short* dst = wt + (size_t)(p * H_ + h) * D_ * E_;
  const int r0 = blockIdx.x * 64;  // e-tile
  const int lr = threadIdx.x >> 4, lc = (threadIdx.x & 15) * 4;
#pragma unroll
  for (int it = 0; it < 4; it++) {
    const float4 f = *(const float4*)(src + (size_t)(r0 + lr + it * 16) * D_ + lc);
    ts[lr + it * 16][lc] = f.x; ts[lr + it * 16][lc + 1] = f.y;
    ts[lr + it * 16][lc + 2] = f.z; ts[lr + it * 16][lc + 3] = f.w;
  }
  __syncthreads();
#pragma unroll
  for (int it = 0; it < 4; it++) {
    const int dr = lr + it * 16;  // d
    ushort4 pk;
    pk.x = f2h(ts[lc + 0][dr]); pk.y = f2h(ts[lc + 1][dr]);
    pk.z = f2h(ts[lc + 2][dr]); pk.w = f2h(ts[lc + 3][dr]);
    *(ushort4*)(dst + (size_t)dr * E_ + r0 + lc) = pk;
  }
}

// ---------------------------------------------------------------------------
// Prep 2: Wo [e][j] fp32 -> wot [j][e] fp16. grid=(16,16).
// ---------------------------------------------------------------------------
__global__ __launch_bounds__(256) void tconv_wo(const float* __restrict__ Wo,
                                                unsigned short* __restrict__ wot) {
  __shared__ float ts[64][65];
  const int r0 = blockIdx.x * 64;  // e-tile
  const int c0 = blockIdx.y * 64;  // j-tile
  const int lr = threadIdx.x >> 4, lc = (threadIdx.x & 15) * 4;
#pragma unroll
  for (int it = 0; it < 4; it++) {
    const float4 f = *(const float4*)(Wo + (size_t)(r0 + lr + it * 16) * E_ + c0 + lc);
    ts[lr + it * 16][lc] = f.x; ts[lr + it * 16][lc + 1] = f.y;
    ts[lr + it * 16][lc + 2] = f.z; ts[lr + it * 16][lc + 3] = f.w;
  }
  __syncthreads();
#pragma unroll
  for (int it = 0; it < 4; it++) {
    const int dr = lr + it * 16;  // j within tile
    ushort4 pk;
    pk.x = f2h(ts[lc + 0][dr]); pk.y = f2h(ts[lc + 1][dr]);
    pk.z = f2h(ts[lc + 2][dr]); pk.w = f2h(ts[lc + 3][dr]);
    *(ushort4*)(wot + (size_t)(c0 + dr) * E_ + r0 + lc) = pk;
  }
}

// ---------------------------------------------------------------------------
// Kernel 1: QKV projections via MFMA, coalesced LDS staging.
// grid=(B*T/128, H, 3), block=256 (4 waves).
// ---------------------------------------------------------------------------
__global__ __launch_bounds__(256) void qkv_mfma(
    const unsigned short* __restrict__ xh, const unsigned short* __restrict__ wt,
    unsigned short* __restrict__ qo, unsigned short* __restrict__ ko,
    unsigned short* __restrict__ vo)
{
  __shared__ unsigned short xs[128 * LD_];   // [token][e]
  __shared__ unsigned short wsb[64 * LD_];   // [d][e]
  __shared__ unsigned short Cl[4][32 * 72];  // per-wave repack tile

  const int tid = threadIdx.x;
  const int w = tid >> 6, lane = tid & 63;
  const int m16 = lane & 15, quad = lane >> 4;
  const int h = blockIdx.y, p = blockIdx.z;
  const int n0 = blockIdx.x * 128;           // block token base
  const unsigned short* wb = wt + (size_t)(p * H_ + h) * D_ * E_;

  const int sr = tid >> 3;          // 0..31
  const int sc = (tid & 7) * 8;     // 0,8,...,56

  f32x4 acc[2][4];
#pragma unroll
  for (int rt = 0; rt < 2; rt++)
#pragma unroll
    for (int ct = 0; ct < 4; ct++) acc[rt][ct] = (f32x4){0.f, 0.f, 0.f, 0.f};

  for (int e0 = 0; e0 < E_; e0 += 64) {
    __syncthreads();
#pragma unroll
    for (int it = 0; it < 4; it++) {
      const int row = it * 32 + sr;
      *(uint4*)(xs + row * LD_ + sc) =
          *(const uint4*)(xh + (size_t)(n0 + row) * E_ + e0 + sc);
    }
#pragma unroll
    for (int it = 0; it < 2; it++) {
      const int row = it * 32 + sr;
      *(uint4*)(wsb + row * LD_ + sc) =
          *(const uint4*)(wb + (size_t)row * E_ + e0 + sc);
    }
    __syncthreads();

#pragma unroll
    for (int kk = 0; kk < 64; kk += 32) {
      U4 a0, a1, bf[4];
      a0.u = *(const uint4*)(xs + (w * 32 + m16) * LD_ + kk + quad * 8);
      a1.u = *(const uint4*)(xs + (w * 32 + 16 + m16) * LD_ + kk + quad * 8);
#pragma unroll
      for (int ct = 0; ct < 4; ct++)
        bf[ct].u = *(const uint4*)(wsb + (ct * 16 + m16) * LD_ + kk + quad * 8);
#pragma unroll
      for (int ct = 0; ct < 4; ct++) {
        acc[0][ct] = __builtin_amdgcn_mfma_f32_16x16x32_f16(a0.h, bf[ct].h, acc[0][ct], 0, 0, 0);
        acc[1][ct] = __builtin_amdgcn_mfma_f32_16x16x32_f16(a1.h, bf[ct].h, acc[1][ct], 0, 0, 0);
      }
    }
  }

  const int nw = n0 + w * 32;               // wave token base
  const int b  = n0 >> 11;                  // batch (128 | 2048, never straddles)
  const int t0 = nw & (T_ - 1);
  const size_t bh = (size_t)(b * H_ + h);

  if (p == 2) {
#pragma unroll
    for (int rt = 0; rt < 2; rt++)
#pragma unroll
      for (int ct = 0; ct < 4; ct++) {
        const int d = ct * 16 + m16;
        const int t = t0 + rt * 16 + quad * 4;
        ushort4 pk;
        pk.x = f2h(acc[rt][ct][0]); pk.y = f2h(acc[rt][ct][1]);
        pk.z = f2h(acc[rt][ct][2]); pk.w = f2h(acc[rt][ct][3]);
        *(ushort4*)(vo + (bh * D_ + d) * (size_t)VTS_ + t) = pk;
      }
  } else {
    unsigned short* outp = (p == 0) ? qo : ko;
    unsigned short* Cw = &Cl[w][0];
#pragma unroll
    for (int rt = 0; rt < 2; rt++)
#pragma unroll
      for (int ct = 0; ct < 4; ct++)
#pragma unroll
        for (int r = 0; r < 4; r++)
          Cw[(rt * 16 + quad * 4 + r) * 72 + ct * 16 + m16] = f2h(acc[rt][ct][r]);
    const int row = lane >> 1;
    const int half = (lane & 1) * 32;
    const uint4 d0 = *(const uint4*)(Cw + row * 72 + half);
    const uint4 d1 = *(const uint4*)(Cw + row * 72 + half + 8);
    const uint4 d2 = *(const uint4*)(Cw + row * 72 + half + 16);
    const uint4 d3 = *(const uint4*)(Cw + row * 72 + half + 24);
    unsigned short* dst = outp + (bh * T_ + t0 + row) * D_ + half;
    *(uint4*)(dst)      = d0;
    *(uint4*)(dst + 8)  = d1;
    *(uint4*)(dst + 16) = d2;
    *(uint4*)(dst + 24) = d3;
  }
}

// ---------------------------------------------------------------------------
// Kernel 2: MFMA flash attention, fully in-register softmax (round-11).
// grid=(T/64, H, B), block=256 (4 waves = 4 Q-tiles of 16 rows).
//
// Swapped QK^T: st = mfma(K_frag, Q_frag) = S^T tile, so lane (m16,quad)
// holds S[q=m16][key = ct*16 + quad*4 + r].  Row stats: in-lane trees +
// shfl_xor(16/32).  The exp'd values are directly the A-fragment of
// mfma_f32_16x16x16f16 (lane (m16,q) holds A[m16][q*4+j]) -> P never
// touches LDS.  Per-output-row alpha / 1/l fetched with 4 bpermutes.
// K/V LDS is double-buffered; tile t+1 global loads issue before compute(t).
// ---------------------------------------------------------------------------
__global__ __launch_bounds__(256) void attn_kernel(
    const unsigned short* __restrict__ q, const unsigned short* __restrict__ k,
    const unsigned short* __restrict__ vt, unsigned short* __restrict__ comb)
{
  __shared__ unsigned short Kt[2][64 * LD_];   // [key][d]
  __shared__ unsigned short Vt[2][64 * LD_];   // [d][key]

  const int tid  = threadIdx.x;
  const int w    = tid >> 6;
  const int lane = tid & 63;
  const int m16  = lane & 15;
  const int quad = lane >> 4;
  const int h = blockIdx.y, b = blockIdx.z;
  const size_t bh = (size_t)(b * H_ + h);
  const int q0 = blockIdx.x * 64 + w * 16;

  // Q fragments; 1/sqrt(D)=0.125 folded in (exact power-of-2 scale in fp16).
  U4 aQ0, aQ1;
  {
    const unsigned short* qrow = q + (bh * T_ + q0 + m16) * (size_t)D_;
    aQ0.u = *(const uint4*)(qrow + quad * 8);
    aQ1.u = *(const uint4*)(qrow + 32 + quad * 8);
    aQ0.h = aQ0.h * (_Float16)0.125f;
    aQ1.h = aQ1.h * (_Float16)0.125f;
  }

  f32x4 o0 = {0.f, 0.f, 0.f, 0.f}, o1 = o0, o2 = o0, o3 = o0;
  float mrow = -1e30f;   // running max of q-row m16 (replicated across quads)
  float lrow = 0.f;      // running denom of q-row m16

  const unsigned short* kb  = k  + bh * (size_t)(T_ * D_);
  const unsigned short* vtb = vt + bh * (size_t)(D_ * VTS_);

  const int sr = tid >> 3;          // 0..31
  const int sc = (tid & 7) * 8;     // 0,8,...,56

  uint4 kr0, kr1, vr0, vr1;
  // prologue: stage tile 0
  kr0 = *(const uint4*)(kb + (size_t)sr * D_ + sc);
  kr1 = *(const uint4*)(kb + (size_t)(32 + sr) * D_ + sc);
  vr0 = *(const uint4*)(vtb + (size_t)sr * VTS_ + sc);
  vr1 = *(const uint4*)(vtb + (size_t)(32 + sr) * VTS_ + sc);
  *(uint4*)(&Kt[0][0] + sr * LD_ + sc)        = kr0;
  *(uint4*)(&Kt[0][0] + (32 + sr) * LD_ + sc) = kr1;
  *(uint4*)(&Vt[0][0] + sr * LD_ + sc)        = vr0;
  *(uint4*)(&Vt[0][0] + (32 + sr) * LD_ + sc) = vr1;
  __syncthreads();

  const int NT = T_ / 64;
  for (int t = 0; t < NT; t++) {
    const int cur = t & 1;
    const unsigned short* Kc = &Kt[cur][0];
    const unsigned short* Vc = &Vt[cur][0];
    const bool more = (t + 1 < NT);
    if (more) {
      const int kt = (t + 1) * 64;   // issue next tile a full compute early
      kr0 = *(const uint4*)(kb + (size_t)(kt + sr) * D_ + sc);
      kr1 = *(const uint4*)(kb + (size_t)(kt + 32 + sr) * D_ + sc);
      vr0 = *(const uint4*)(vtb + (size_t)sr * VTS_ + kt + sc);
      vr1 = *(const uint4*)(vtb + (size_t)(32 + sr) * VTS_ + kt + sc);
    }

    // QK^T swapped: st[ct][r] = S[q=m16][key = ct*16 + quad*4 + r] (scaled)
    f32x4 st[4];
#pragma unroll
    for (int ct = 0; ct < 4; ct++) {
      U4 kf0, kf1;
      kf0.u = *(const uint4*)(Kc + (ct * 16 + m16) * LD_ + quad * 8);
      kf1.u = *(const uint4*)(Kc + (ct * 16 + m16) * LD_ + 32 + quad * 8);
      f32x4 z = {0.f, 0.f, 0.f, 0.f};
      z = __builtin_amdgcn_mfma_f32_16x16x32_f16(kf0.h, aQ0.h, z, 0, 0, 0);
      z = __builtin_amdgcn_mfma_f32_16x16x32_f16(kf1.h, aQ1.h, z, 0, 0, 0);
      st[ct] = z;
    }

    // row max: lane-local tree over 16 keys, then combine across quads
    const float m0 = fmaxf(fmaxf(st[0][0], st[0][1]), fmaxf(st[0][2], st[0][3]));
    const float m1 = fmaxf(fmaxf(st[1][0], st[1][1]), fmaxf(st[1][2], st[1][3]));
    const float m2 = fmaxf(fmaxf(st[2][0], st[2][1]), fmaxf(st[2][2], st[2][3]));
    const float m3 = fmaxf(fmaxf(st[3][0], st[3][1]), fmaxf(st[3][2], st[3][3]));
    float ml = fmaxf(fmaxf(m0, m1), fmaxf(m2, m3));
    ml = fmaxf(ml, __shfl_xor(ml, 16));
    ml = fmaxf(ml, __shfl_xor(ml, 32));

    const float mn = fmaxf(mrow, ml);
    const float a  = __expf(mrow - mn);
    mrow = mn;

    // exp + row sum; packed values directly form PV A-fragments
    float sl = 0.f;
    h4 pf[4];
#pragma unroll
    for (int ct = 0; ct < 4; ct++) {
      const float e0 = __expf(st[ct][0] - mn);
      const float e1 = __expf(st[ct][1] - mn);
      const float e2 = __expf(st[ct][2] - mn);
      const float e3 = __expf(st[ct][3] - mn);
      sl += (e0 + e1) + (e2 + e3);
      pf[ct] = (h4){(_Float16)e0, (_Float16)e1, (_Float16)e2, (_Float16)e3};
    }
    sl += __shfl_xor(sl, 16);
    sl += __shfl_xor(sl, 32);
    lrow = lrow * a + sl;

    // rescale O: alpha for output rows quad*4+r lives in lanes 0..15
    float al[4];
#pragma unroll
    for (int r = 0; r < 4; r++) al[r] = __shfl(a, quad * 4 + r);
#pragma unroll
    for (int r = 0; r < 4; r++) {
      o0[r] *= al[r]; o1[r] *= al[r]; o2[r] *= al[r]; o3[r] *= al[r];
    }

    // PV: 16x16x16 MFMAs; B-frag is a b64 LDS read (2-way bank alias = free)
#pragma unroll
    for (int ctd = 0; ctd < 4; ctd++) {
      f32x4* op = (ctd == 0) ? &o0 : (ctd == 1) ? &o1 : (ctd == 2) ? &o2 : &o3;
      const unsigned short* vrw = Vc + (ctd * 16 + m16) * LD_ + quad * 4;
#pragma unroll
      for (int ctk = 0; ctk < 4; ctk++) {
        const h4 vf = *(const h4*)(vrw + ctk * 16);
        *op = __builtin_amdgcn_mfma_f32_16x16x16f16(pf[ctk], vf, *op, 0, 0, 0);
      }
    }

    if (more) {
      __syncthreads();   // all waves done reading buf[cur^1] (tile t-1)
      unsigned short* Kn = &Kt[cur ^ 1][0];
      unsigned short* Vn = &Vt[cur ^ 1][0];
      *(uint4*)(Kn + sr * LD_ + sc)        = kr0;
      *(uint4*)(Kn + (32 + sr) * LD_ + sc) = kr1;
      *(uint4*)(Vn + sr * LD_ + sc)        = vr0;
      *(uint4*)(Vn + (32 + sr) * LD_ + sc) = vr1;
      __syncthreads();   // writes visible before compute(t+1)
    }
  }

  float linv[4];
#pragma unroll
  for (int r = 0; r < 4; r++) linv[r] = 1.f / __shfl(lrow, quad * 4 + r);

#pragma unroll
  for (int r = 0; r < 4; r++) {
    const int tq = q0 + quad * 4 + r;
    unsigned short* dst = comb + ((size_t)b * T_ + tq) * E_ + h * D_;
    dst[m16]      = f2h(o0[r] * linv[r]);
    dst[16 + m16] = f2h(o1[r] * linv[r]);
    dst[32 + m16] = f2h(o2[r] * linv[r]);
    dst[48 + m16] = f2h(o3[r] * linv[r]);
  }
}

// ---------------------------------------------------------------------------
// Kernel 3: out = comb @ Wo + x, coalesced LDS staging.
// grid=(B*T/128, E/64), block=256 (4 waves). Block: 128 n x 64 j.
// ---------------------------------------------------------------------------
__global__ __launch_bounds__(256) void out_mfma(
    const unsigned short* __restrict__ comb, const unsigned short* __restrict__ wot,
    const float* __restrict__ x, float* __restrict__ out)
{
  __shared__ unsigned short cs[128 * LD_];   // [n][e]
  __shared__ unsigned short wsb[64 * LD_];   // [j][e]

  const int tid = threadIdx.x;
  const int w = tid >> 6, lane = tid & 63;
  const int m16 = lane & 15, quad = lane >> 4;
  const int n0 = blockIdx.x * 128;
  const int j0 = blockIdx.y * 64;

  const int sr = tid >> 3;          // 0..31
  const int sc = (tid & 7) * 8;     // 0,8,...,56

  f32x4 acc[2][4];
#pragma unroll
  for (int rt = 0; rt < 2; rt++)
#pragma unroll
    for (int ct = 0; ct < 4; ct++) acc[rt][ct] = (f32x4){0.f, 0.f, 0.f, 0.f};

  for (int e0 = 0; e0 < E_; e0 += 64) {
    __syncthreads();
#pragma unroll
    for (int it = 0; it < 4; it++) {
      const int row = it * 32 + sr;
      *(uint4*)(cs + row * LD_ + sc) =
          *(const uint4*)(comb + (size_t)(n0 + row) * E_ + e0 + sc);
    }
#pragma unroll
    for (int it = 0; it < 2; it++) {
      const int row = it * 32 + sr;
      *(uint4*)(wsb + row * LD_ + sc) =
          *(const uint4*)(wot + (size_t)(j0 + row) * E_ + e0 + sc);
    }
    __syncthreads();

#pragma unroll
    for (int kk = 0; kk < 64; kk += 32) {
      U4 a0, a1, bf[4];
      a0.u = *(const uint4*)(cs + (w * 32 + m16) * LD_ + kk + quad * 8);
      a1.u = *(const uint4*)(cs + (w * 32 + 16 + m16) * LD_ + kk + quad * 8);
#pragma unroll
      for (int ct = 0; ct < 4; ct++)
        bf[ct].u = *(const uint4*)(wsb + (ct * 16 + m16) * LD_ + kk + quad * 8);
#pragma unroll
      for (int ct = 0; ct < 4; ct++) {
        acc[0][ct] = __builtin_amdgcn_mfma_f32_16x16x32_f16(a0.h, bf[ct].h, acc[0][ct], 0, 0, 0);
        acc[1][ct] = __builtin_amdgcn_mfma_f32_16x16x32_f16(a1.h, bf[ct].h, acc[1][ct], 0, 0, 0);
      }
    }
  }

  const int nw = n0 + w * 32;
#pragma unroll
  for (int rt = 0; rt < 2; rt++)
#pragma unroll
    for (int r = 0; r < 4; r++) {
      const int n = nw + rt * 16 + quad * 4 + r;
      const float* xr = x + (size_t)n * E_ + j0;
      float* orow = out + (size_t)n * E_ + j0;
#pragma unroll
      for (int ct = 0; ct < 4; ct++) {
        const int j = ct * 16 + m16;
        orow[j] = acc[rt][ct][r] + xr[j];
      }
    }
}

// ---------------------------------------------------------------------------
extern "C" void kernel_launch(void* const* d_in, const int* in_sizes, int n_in,
                              void* d_out, int out_size, void* d_ws, size_t ws_size,
                              hipStream_t stream) {
  (void)in_sizes; (void)n_in; (void)out_size; (void)ws_size;

  const float* x  = (const float*)d_in[0];
  const float* Wq = (const float*)d_in[1];
  const float* Wk = (const float*)d_in[2];
  const float* Wv = (const float*)d_in[3];
  const float* Wo = (const float*)d_in[4];
  float* out = (float*)d_out;

  unsigned short* ws0  = (unsigned short*)d_ws;
  unsigned short* xh   = ws0;                    // 4M elems (aliases comb)
  unsigned short* wt   = ws0 + 4194304;          // 3M
  unsigned short* wot  = ws0 + 7340032;          // 1M
  unsigned short* qh   = ws0 + 8388608;          // 4M
  unsigned short* kh   = ws0 + 12582912;         // 4M
  unsigned short* vth  = ws0 + 16777216;         // 32*64*2176 = 4.46M (padded)
  unsigned short* comb = xh;                     // alias: xh dead after qkv

  cvt_x<<<dim3(B_ * T_ * E_ / 1024), dim3(256), 0, stream>>>(x, xh);
  tconv_w<<<dim3(E_ / 64, H_, 3), dim3(256), 0, stream>>>(Wq, Wk, Wv, wt);
  tconv_wo<<<dim3(E_ / 64, E_ / 64), dim3(256), 0, stream>>>(Wo, wot);

  qkv_mfma<<<dim3(B_ * T_ / 128, H_, 3), dim3(256), 0, stream>>>(xh, wt, qh, kh, vth);

  attn_kernel<<<dim3(T_ / 64, H_, B_), dim3(256), 0, stream>>>(qh, kh, vth, comb);

  out_mfma<<<dim3(B_ * T_ / 128, E_ / 64), dim3(256), 0, stream>>>(comb, wot, x, out);
}